// Round 8
// baseline (83.044 us; speedup 1.0000x reference)
//
#include <hip/hip_runtime.h>
#include <math.h>

#define B 8
#define L 8192
#define H 1024
#define SCALE 0.03125f   // 1/sqrt(1024)

#define MAX_N 160        // >= 129 cantor keys
#define CPB   128        // colsum blocks per batch
#define ROWSC (L / CPB)  // 64 rows per colsum block
#define NPART CPB        // partial rows per batch

// ws layout (float offsets) — total (2*B*H + NPART*B*H)*4 = 4.26 MB < ws_size.
//   OFF_OUTS: hil_out (B*H) then can_out (B*H)
//   OFF_PART: partials (NPART*B*H), layout [p][b][h]
#define OFF_OUTS 0
#define OFF_PART (2 * B * H)

__device__ inline void d2xy_dev(int n, int d, int* px, int* py) {
    int x = 0, y = 0;
    for (int s = 1; s < n; s *= 2) {
        int rx = 1 & (d / 2);
        int ry = 1 & (d ^ rx);
        if (ry == 0) {
            if (rx == 1) { x = s - 1 - x; y = s - 1 - y; }
            int t = x; x = y; y = t;
        }
        x += s * rx; y += s * ry;
        d /= 4;
    }
    *px = x; *py = y;
}

__device__ inline int xy2d_dev(int n, int x, int y) {
    int d = 0;
    for (int s = n / 2; s > 0; s /= 2) {
        int rx = ((x & s) > 0) ? 1 : 0;
        int ry = ((y & s) > 0) ? 1 : 0;
        d += s * s * ((3 * rx) ^ ry);
        if (ry == 0) {
            if (rx == 1) { x = s - 1 - x; y = s - 1 - y; }
            int t = x; x = y; y = t;
        }
    }
    return d;
}

// Blocks 0..15: fused sparse attention (set = bid>>3, b = bid&7).
// Blocks 16..16+1024-1: colsum partial over a 64-row slice of v
// (bandwidth shape: 256 threads, float4 loads, no LDS/sync).
__global__ __launch_bounds__(256)
void mega_kernel(const float* __restrict__ q, const float* __restrict__ k,
                 const float* __restrict__ v, const int* __restrict__ qidx_p,
                 float* __restrict__ ws_f) {
    int bid = blockIdx.x;
    int tid = threadIdx.x;

    if (bid >= 16) {
        // ---------------- colsum partial (dragon mean) ----------------
        int cb = bid - 16;
        int b  = cb >> 7;        // 128 blocks per batch
        int kp = cb & 127;       // 64-row slice

        const float4* base =
            (const float4*)(v + ((size_t)b * L + (size_t)kp * ROWSC) * H);
        float4 acc = make_float4(0.f, 0.f, 0.f, 0.f);
        #pragma unroll 8
        for (int r = 0; r < ROWSC; r++) {
            float4 x = base[(size_t)r * (H / 4) + tid];
            acc.x += x.x; acc.y += x.y; acc.z += x.z; acc.w += x.w;
        }
        ((float4*)(ws_f + OFF_PART + ((size_t)kp * B + b) * H))[tid] = acc;
        return;
    }

    // ---------------- fused sparse attention ----------------
    int set = bid >> 3;   // 0 = hilbert, 1 = cantor
    int b   = bid & 7;

    __shared__ float qs[H];
    __shared__ float sc[MAX_N];
    __shared__ float probs[MAX_N];
    __shared__ int   idx[MAX_N];
    __shared__ int   n_sh;
    __shared__ float sinv_sh;

    // stage q row (256 float4 == 256 threads)
    ((float4*)qs)[tid] = ((const float4*)(q + (size_t)b * H))[tid];

    if (set == 1) {
        // Cantor: closed-form per-lane walk of the 7-bit interval path.
        // Final positions are m/3^7; idx = m*8191/2187 is never within
        // 4.6e-4 of an integer -> truncation matches numpy; all distinct.
        if (tid < 129) {
            double l = (tid == 128) ? 1.0 : 0.0;
            if (tid < 128) {
                double gap = 1.0;
                #pragma unroll
                for (int bit = 6; bit >= 0; --bit) {
                    double third = gap / 3.0;
                    if ((tid >> bit) & 1) { l += third; gap -= third; }
                    else                  { gap = third; }
                }
            }
            idx[tid] = (int)(l * (double)(L - 1));
        }
        if (tid == 0) n_sh = 129;
    } else {
        // Hilbert: 49 candidates on wave 0, ballot-compact (order is
        // irrelevant: softmax+sum is permutation-invariant).
        if (tid < 64) {
            int center = qidx_p[0];
            if (center > 9999) center = 9999;
            if (center < 0) center = 0;
            int cx, cy;
            d2xy_dev(128, center, &cx, &cy);
            int val = -1;
            if (tid < 49) {
                int x = cx + tid / 7 - 3, y = cy + tid % 7 - 3;
                if (x >= 0 && x < 128 && y >= 0 && y < 128) {
                    int i = xy2d_dev(128, x, y);
                    if (i < L) val = i;
                }
            }
            unsigned long long ball = __ballot(val >= 0);
            int pos = __popcll(ball & ((1ull << tid) - 1));
            if (val >= 0) idx[pos] = val;
            if (tid == 0) n_sh = __popcll(ball);
        }
    }
    __syncthreads();
    int n = n_sh;

    // scores: wave per key (4 waves)
    int wid = tid >> 6, lane = tid & 63;
    for (int j = wid; j < n; j += 4) {
        const float4* k4 =
            (const float4*)(k + ((size_t)b * L + (size_t)idx[j]) * H);
        float p = 0.f;
        #pragma unroll
        for (int i = 0; i < H / 256; i++) {
            float4 a = ((float4*)qs)[lane + i * 64];
            float4 c = k4[lane + i * 64];
            p += a.x * c.x + a.y * c.y + a.z * c.z + a.w * c.w;
        }
        #pragma unroll
        for (int off = 32; off; off >>= 1) p += __shfl_down(p, off);
        if (lane == 0) sc[j] = p * SCALE;
    }
    __syncthreads();

    // softmax on wave 0
    if (wid == 0) {
        float m = -1e30f;
        for (int j = lane; j < n; j += 64) m = fmaxf(m, sc[j]);
        #pragma unroll
        for (int mask = 32; mask; mask >>= 1) m = fmaxf(m, __shfl_xor(m, mask));
        float s = 0.f;
        for (int j = lane; j < n; j += 64) {
            float e = expf(sc[j] - m);
            probs[j] = e;
            s += e;
        }
        #pragma unroll
        for (int mask = 32; mask; mask >>= 1) s += __shfl_xor(s, mask);
        if (lane == 0) sinv_sh = 1.f / s;
    }
    __syncthreads();

    // PV: thread owns float4 column tid
    float4 acc = make_float4(0.f, 0.f, 0.f, 0.f);
    #pragma unroll 4
    for (int j = 0; j < n; j++) {
        float p = probs[j];
        float4 x = ((const float4*)(v + ((size_t)b * L + (size_t)idx[j]) * H))[tid];
        acc.x += p * x.x; acc.y += p * x.y; acc.z += p * x.z; acc.w += p * x.w;
    }
    float sinv = sinv_sh;
    float4 o = make_float4(acc.x * sinv, acc.y * sinv, acc.z * sinv, acc.w * sinv);
    ((float4*)(ws_f + OFF_OUTS + ((size_t)set * B + b) * H))[tid] = o;
}

// 8 blocks x 256 threads: thread owns one float4 column of one batch.
__global__ __launch_bounds__(256)
void combine_kernel(const float* __restrict__ pw, const float* __restrict__ ws_f,
                    float* __restrict__ out) {
    int b = blockIdx.x;
    int c4 = threadIdx.x;
    float w0 = pw[0], w1 = pw[1], w2 = pw[2];
    float m  = fmaxf(w0, fmaxf(w1, w2));
    float e0 = expf(w0 - m), e1 = expf(w1 - m), e2 = expf(w2 - m);
    float invs = 1.f / (e0 + e1 + e2);

    float4 s = make_float4(0.f, 0.f, 0.f, 0.f);
    #pragma unroll 8
    for (int p2 = 0; p2 < NPART; p2++) {   // fixed order -> deterministic
        float4 x = ((const float4*)(ws_f + OFF_PART +
                                    ((size_t)p2 * B + b) * H))[c4];
        s.x += x.x; s.y += x.y; s.z += x.z; s.w += x.w;
    }
    float4 hil = ((const float4*)(ws_f + OFF_OUTS + (size_t)b * H))[c4];
    float4 can = ((const float4*)(ws_f + OFF_OUTS + ((size_t)B + b) * H))[c4];
    const float il = 1.0f / (float)L;  // dragon weights exactly 0 -> uniform attn
    float4 o;
    o.x = (e0 * hil.x + e1 * can.x + e2 * (s.x * il)) * invs;
    o.y = (e0 * hil.y + e1 * can.y + e2 * (s.y * il)) * invs;
    o.z = (e0 * hil.z + e1 * can.z + e2 * (s.z * il)) * invs;
    o.w = (e0 * hil.w + e1 * can.w + e2 * (s.w * il)) * invs;
    ((float4*)(out + (size_t)b * H))[c4] = o;
}

extern "C" void kernel_launch(void* const* d_in, const int* in_sizes, int n_in,
                              void* d_out, int out_size, void* d_ws, size_t ws_size,
                              hipStream_t stream) {
    const float* q  = (const float*)d_in[0];
    const float* k  = (const float*)d_in[1];
    const float* v  = (const float*)d_in[2];
    const float* pw = (const float*)d_in[3];
    const int* qidx = (const int*)d_in[4];

    float* ws_f = (float*)d_ws;

    mega_kernel<<<16 + CPB * B, 256, 0, stream>>>(q, k, v, qidx, ws_f);
    combine_kernel<<<B, 256, 0, stream>>>(pw, ws_f, (float*)d_out);
}

// Round 9
// 63.205 us; speedup vs baseline: 1.3139x; 1.3139x over previous
//
#include <hip/hip_runtime.h>
#include <math.h>

#define B 8
#define L 8192
#define H 1024
#define SCALE 0.03125f   // 1/sqrt(1024)

#define MAX_N 160        // >= 129 cantor keys
#define CPB   128        // colsum blocks per batch
#define ROWSC (L / CPB)  // 64 rows per colsum block
#define NPART CPB        // partial rows per batch

// ws layout (float offsets) — total (2*B*H + NPART*B*H)*4 = 4.26 MB (safe).
//   OFF_OUTS: hil_out (B*H) then can_out (B*H)
//   OFF_PART: partials (NPART*B*H), layout [p][b][h]
#define OFF_OUTS 0
#define OFF_PART (2 * B * H)

__device__ inline void d2xy_dev(int n, int d, int* px, int* py) {
    int x = 0, y = 0;
    for (int s = 1; s < n; s *= 2) {
        int rx = 1 & (d / 2);
        int ry = 1 & (d ^ rx);
        if (ry == 0) {
            if (rx == 1) { x = s - 1 - x; y = s - 1 - y; }
            int t = x; x = y; y = t;
        }
        x += s * rx; y += s * ry;
        d /= 4;
    }
    *px = x; *py = y;
}

__device__ inline int xy2d_dev(int n, int x, int y) {
    int d = 0;
    for (int s = n / 2; s > 0; s /= 2) {
        int rx = ((x & s) > 0) ? 1 : 0;
        int ry = ((y & s) > 0) ? 1 : 0;
        d += s * s * ((3 * rx) ^ ry);
        if (ry == 0) {
            if (rx == 1) { x = s - 1 - x; y = s - 1 - y; }
            int t = x; x = y; y = t;
        }
    }
    return d;
}

// Blocks 0..15: fused sparse attention (set = bid>>3, b = bid&7).
// Blocks 16..1039: colsum partial over a 64-row slice of v.
// 1040 blocks x 512 threads -> 4 blocks/CU -> full 32 waves/CU occupancy.
__global__ __launch_bounds__(512)
void mega_kernel(const float* __restrict__ q, const float* __restrict__ k,
                 const float* __restrict__ v, const int* __restrict__ qidx_p,
                 float* __restrict__ ws_f) {
    int bid = blockIdx.x;
    int tid = threadIdx.x;

    if (bid >= 16) {
        // ---------------- colsum partial (dragon mean) ----------------
        // Thread owns one float2 column across 64 rows (8 B/lane, no LDS).
        int cb = bid - 16;
        int b  = cb >> 7;        // 128 blocks per batch
        int kp = cb & 127;       // 64-row slice

        const float2* base =
            (const float2*)(v + ((size_t)b * L + (size_t)kp * ROWSC) * H);
        float ax = 0.f, ay = 0.f;
        #pragma unroll 8
        for (int r = 0; r < ROWSC; r++) {
            float2 x = base[(size_t)r * (H / 2) + tid];
            ax += x.x; ay += x.y;
        }
        ((float2*)(ws_f + OFF_PART + ((size_t)kp * B + b) * H))[tid] =
            make_float2(ax, ay);
        return;
    }

    // ---------------- fused sparse attention ----------------
    int set = bid >> 3;   // 0 = hilbert, 1 = cantor
    int b   = bid & 7;

    __shared__ float qs[H];
    __shared__ float sc[MAX_N];
    __shared__ float probs[MAX_N];
    __shared__ int   idx[MAX_N];
    __shared__ int   n_sh;
    __shared__ float sinv_sh;

    if (tid < H / 4)
        ((float4*)qs)[tid] = ((const float4*)(q + (size_t)b * H))[tid];

    if (set == 1) {
        // Cantor: closed-form per-lane walk of the 7-bit interval path.
        // Final positions are m/3^7; idx = m*8191/2187 is never within
        // 4.6e-4 of an integer -> truncation matches numpy; all distinct.
        if (tid < 129) {
            double l = (tid == 128) ? 1.0 : 0.0;
            if (tid < 128) {
                double gap = 1.0;
                #pragma unroll
                for (int bit = 6; bit >= 0; --bit) {
                    double third = gap / 3.0;
                    if ((tid >> bit) & 1) { l += third; gap -= third; }
                    else                  { gap = third; }
                }
            }
            idx[tid] = (int)(l * (double)(L - 1));
        }
        if (tid == 0) n_sh = 129;
    } else {
        // Hilbert: 49 candidates on wave 0, ballot-compact (order is
        // irrelevant: softmax+sum is permutation-invariant).
        if (tid < 64) {
            int center = qidx_p[0];
            if (center > 9999) center = 9999;
            if (center < 0) center = 0;
            int cx, cy;
            d2xy_dev(128, center, &cx, &cy);
            int val = -1;
            if (tid < 49) {
                int x = cx + tid / 7 - 3, y = cy + tid % 7 - 3;
                if (x >= 0 && x < 128 && y >= 0 && y < 128) {
                    int i = xy2d_dev(128, x, y);
                    if (i < L) val = i;
                }
            }
            unsigned long long ball = __ballot(val >= 0);
            int pos = __popcll(ball & ((1ull << tid) - 1));
            if (val >= 0) idx[pos] = val;
            if (tid == 0) n_sh = __popcll(ball);
        }
    }
    __syncthreads();
    int n = n_sh;

    // scores: wave per key (8 waves)
    int wid = tid >> 6, lane = tid & 63;
    for (int j = wid; j < n; j += 8) {
        const float4* k4 =
            (const float4*)(k + ((size_t)b * L + (size_t)idx[j]) * H);
        float p = 0.f;
        #pragma unroll
        for (int i = 0; i < H / 256; i++) {
            float4 a = ((float4*)qs)[lane + i * 64];
            float4 c = k4[lane + i * 64];
            p += a.x * c.x + a.y * c.y + a.z * c.z + a.w * c.w;
        }
        #pragma unroll
        for (int off = 32; off; off >>= 1) p += __shfl_down(p, off);
        if (lane == 0) sc[j] = p * SCALE;
    }
    __syncthreads();

    // softmax on wave 0
    if (wid == 0) {
        float m = -1e30f;
        for (int j = lane; j < n; j += 64) m = fmaxf(m, sc[j]);
        #pragma unroll
        for (int mask = 32; mask; mask >>= 1) m = fmaxf(m, __shfl_xor(m, mask));
        float s = 0.f;
        for (int j = lane; j < n; j += 64) {
            float e = expf(sc[j] - m);
            probs[j] = e;
            s += e;
        }
        #pragma unroll
        for (int mask = 32; mask; mask >>= 1) s += __shfl_xor(s, mask);
        if (lane == 0) sinv_sh = 1.f / s;
    }
    __syncthreads();

    // PV: thread owns float2 column pair (2*tid, 2*tid+1)
    float ax = 0.f, ay = 0.f;
    #pragma unroll 8
    for (int j = 0; j < n; j++) {
        float p = probs[j];
        const float2 x =
            *(const float2*)(v + ((size_t)b * L + (size_t)idx[j]) * H + 2 * tid);
        ax += p * x.x; ay += p * x.y;
    }
    float sinv = sinv_sh;
    ((float2*)(ws_f + OFF_OUTS + ((size_t)set * B + b) * H))[tid] =
        make_float2(ax * sinv, ay * sinv);
}

// 8 blocks x 256 threads: thread owns one float4 column of one batch.
__global__ __launch_bounds__(256)
void combine_kernel(const float* __restrict__ pw, const float* __restrict__ ws_f,
                    float* __restrict__ out) {
    int b = blockIdx.x;
    int c4 = threadIdx.x;
    float w0 = pw[0], w1 = pw[1], w2 = pw[2];
    float m  = fmaxf(w0, fmaxf(w1, w2));
    float e0 = expf(w0 - m), e1 = expf(w1 - m), e2 = expf(w2 - m);
    float invs = 1.f / (e0 + e1 + e2);

    float4 s = make_float4(0.f, 0.f, 0.f, 0.f);
    #pragma unroll 8
    for (int p2 = 0; p2 < NPART; p2++) {   // fixed order -> deterministic
        float4 x = ((const float4*)(ws_f + OFF_PART +
                                    ((size_t)p2 * B + b) * H))[c4];
        s.x += x.x; s.y += x.y; s.z += x.z; s.w += x.w;
    }
    float4 hil = ((const float4*)(ws_f + OFF_OUTS + (size_t)b * H))[c4];
    float4 can = ((const float4*)(ws_f + OFF_OUTS + ((size_t)B + b) * H))[c4];
    const float il = 1.0f / (float)L;  // dragon weights exactly 0 -> uniform attn
    float4 o;
    o.x = (e0 * hil.x + e1 * can.x + e2 * (s.x * il)) * invs;
    o.y = (e0 * hil.y + e1 * can.y + e2 * (s.y * il)) * invs;
    o.z = (e0 * hil.z + e1 * can.z + e2 * (s.z * il)) * invs;
    o.w = (e0 * hil.w + e1 * can.w + e2 * (s.w * il)) * invs;
    ((float4*)(out + (size_t)b * H))[c4] = o;
}

extern "C" void kernel_launch(void* const* d_in, const int* in_sizes, int n_in,
                              void* d_out, int out_size, void* d_ws, size_t ws_size,
                              hipStream_t stream) {
    const float* q  = (const float*)d_in[0];
    const float* k  = (const float*)d_in[1];
    const float* v  = (const float*)d_in[2];
    const float* pw = (const float*)d_in[3];
    const int* qidx = (const int*)d_in[4];

    float* ws_f = (float*)d_ws;

    mega_kernel<<<16 + CPB * B, 512, 0, stream>>>(q, k, v, qidx, ws_f);
    combine_kernel<<<B, 256, 0, stream>>>(pw, ws_f, (float*)d_out);
}

// Round 10
// 57.360 us; speedup vs baseline: 1.4478x; 1.1019x over previous
//
#include <hip/hip_runtime.h>
#include <math.h>

#define B 8
#define L 8192
#define H 1024
#define SCALE 0.03125f   // 1/sqrt(1024)

#define MAX_N 160        // >= 129 cantor keys
#define CPB   128        // colsum blocks per batch
#define ROWSC (L / CPB)  // 64 rows per colsum block
#define NPART CPB        // partial rows per batch

// ws layout (float offsets) — total (2*B*H + NPART*B*H)*4 = 4.26 MB (safe).
//   OFF_OUTS: hil_out (B*H) then can_out (B*H)
//   OFF_PART: partials (NPART*B*H), layout [p][b][h]
#define OFF_OUTS 0
#define OFF_PART (2 * B * H)

__device__ inline void d2xy_dev(int n, int d, int* px, int* py) {
    int x = 0, y = 0;
    for (int s = 1; s < n; s *= 2) {
        int rx = 1 & (d / 2);
        int ry = 1 & (d ^ rx);
        if (ry == 0) {
            if (rx == 1) { x = s - 1 - x; y = s - 1 - y; }
            int t = x; x = y; y = t;
        }
        x += s * rx; y += s * ry;
        d /= 4;
    }
    *px = x; *py = y;
}

__device__ inline int xy2d_dev(int n, int x, int y) {
    int d = 0;
    for (int s = n / 2; s > 0; s /= 2) {
        int rx = ((x & s) > 0) ? 1 : 0;
        int ry = ((y & s) > 0) ? 1 : 0;
        d += s * s * ((3 * rx) ^ ry);
        if (ry == 0) {
            if (rx == 1) { x = s - 1 - x; y = s - 1 - y; }
            int t = x; x = y; y = t;
        }
    }
    return d;
}

// Blocks 0..15: fused sparse attention (set = bid>>3, b = bid&7).
// Blocks 16..1039: colsum partial, WINDOWED row interleave: block (b,kp)
// reads rows l = kp + m*128, so the 128 blocks of a batch collectively
// sweep one contiguous 512KB window (8 linear streams machine-wide,
// instead of 1024 private streams -> HBM row-buffer friendly).
__global__ __launch_bounds__(512)
void mega_kernel(const float* __restrict__ q, const float* __restrict__ k,
                 const float* __restrict__ v, const int* __restrict__ qidx_p,
                 float* __restrict__ ws_f) {
    int bid = blockIdx.x;
    int tid = threadIdx.x;

    if (bid >= 16) {
        // ---------------- colsum partial (dragon mean) ----------------
        int cb = bid - 16;
        int b  = cb >> 7;        // 128 blocks per batch
        int kp = cb & 127;       // row-interleave phase

        const float2* vb = (const float2*)(v + (size_t)b * L * H);
        float ax = 0.f, ay = 0.f;
        #pragma unroll 8
        for (int m = 0; m < ROWSC; m++) {
            int l = kp + m * CPB;
            float2 x = vb[(size_t)l * (H / 2) + tid];
            ax += x.x; ay += x.y;
        }
        ((float2*)(ws_f + OFF_PART + ((size_t)kp * B + b) * H))[tid] =
            make_float2(ax, ay);
        return;
    }

    // ---------------- fused sparse attention ----------------
    int set = bid >> 3;   // 0 = hilbert, 1 = cantor
    int b   = bid & 7;

    __shared__ float qs[H];
    __shared__ float sc[MAX_N];
    __shared__ float probs[MAX_N];
    __shared__ int   idx[MAX_N];
    __shared__ int   n_sh;
    __shared__ float sinv_sh;

    if (tid < H / 4)
        ((float4*)qs)[tid] = ((const float4*)(q + (size_t)b * H))[tid];

    if (set == 1) {
        // Cantor: closed-form per-lane walk of the 7-bit interval path.
        // Final positions are m/3^7; idx = m*8191/2187 is never within
        // 4.6e-4 of an integer -> truncation matches numpy; all distinct.
        if (tid < 129) {
            double l = (tid == 128) ? 1.0 : 0.0;
            if (tid < 128) {
                double gap = 1.0;
                #pragma unroll
                for (int bit = 6; bit >= 0; --bit) {
                    double third = gap / 3.0;
                    if ((tid >> bit) & 1) { l += third; gap -= third; }
                    else                  { gap = third; }
                }
            }
            idx[tid] = (int)(l * (double)(L - 1));
        }
        if (tid == 0) n_sh = 129;
    } else {
        // Hilbert: 49 candidates on wave 0, ballot-compact (order is
        // irrelevant: softmax+sum is permutation-invariant).
        if (tid < 64) {
            int center = qidx_p[0];
            if (center > 9999) center = 9999;
            if (center < 0) center = 0;
            int cx, cy;
            d2xy_dev(128, center, &cx, &cy);
            int val = -1;
            if (tid < 49) {
                int x = cx + tid / 7 - 3, y = cy + tid % 7 - 3;
                if (x >= 0 && x < 128 && y >= 0 && y < 128) {
                    int i = xy2d_dev(128, x, y);
                    if (i < L) val = i;
                }
            }
            unsigned long long ball = __ballot(val >= 0);
            int pos = __popcll(ball & ((1ull << tid) - 1));
            if (val >= 0) idx[pos] = val;
            if (tid == 0) n_sh = __popcll(ball);
        }
    }
    __syncthreads();
    int n = n_sh;

    // scores: wave per key (8 waves)
    int wid = tid >> 6, lane = tid & 63;
    for (int j = wid; j < n; j += 8) {
        const float4* k4 =
            (const float4*)(k + ((size_t)b * L + (size_t)idx[j]) * H);
        float p = 0.f;
        #pragma unroll
        for (int i = 0; i < H / 256; i++) {
            float4 a = ((float4*)qs)[lane + i * 64];
            float4 c = k4[lane + i * 64];
            p += a.x * c.x + a.y * c.y + a.z * c.z + a.w * c.w;
        }
        #pragma unroll
        for (int off = 32; off; off >>= 1) p += __shfl_down(p, off);
        if (lane == 0) sc[j] = p * SCALE;
    }
    __syncthreads();

    // softmax on wave 0
    if (wid == 0) {
        float m = -1e30f;
        for (int j = lane; j < n; j += 64) m = fmaxf(m, sc[j]);
        #pragma unroll
        for (int mask = 32; mask; mask >>= 1) m = fmaxf(m, __shfl_xor(m, mask));
        float s = 0.f;
        for (int j = lane; j < n; j += 64) {
            float e = expf(sc[j] - m);
            probs[j] = e;
            s += e;
        }
        #pragma unroll
        for (int mask = 32; mask; mask >>= 1) s += __shfl_xor(s, mask);
        if (lane == 0) sinv_sh = 1.f / s;
    }
    __syncthreads();

    // PV: thread owns float2 column pair (2*tid, 2*tid+1)
    float ax = 0.f, ay = 0.f;
    #pragma unroll 8
    for (int j = 0; j < n; j++) {
        float p = probs[j];
        const float2 x =
            *(const float2*)(v + ((size_t)b * L + (size_t)idx[j]) * H + 2 * tid);
        ax += p * x.x; ay += p * x.y;
    }
    float sinv = sinv_sh;
    ((float2*)(ws_f + OFF_OUTS + ((size_t)set * B + b) * H))[tid] =
        make_float2(ax * sinv, ay * sinv);
}

// grid (B,4) x 256 threads: z-chunk of 64 float4 columns; 4 partial-groups
// of 32 summed per thread, LDS-reduced in fixed order -> deterministic.
__global__ __launch_bounds__(256)
void combine_kernel(const float* __restrict__ pw, const float* __restrict__ ws_f,
                    float* __restrict__ out) {
    int b    = blockIdx.x;
    int z    = blockIdx.y;
    int t    = threadIdx.x;
    int lane = t & 63;
    int psub = t >> 6;          // 0..3
    int c4   = z * 64 + lane;   // float4 column

    float4 s = make_float4(0.f, 0.f, 0.f, 0.f);
    #pragma unroll 8
    for (int i = 0; i < NPART / 4; i++) {
        int p = psub * (NPART / 4) + i;
        float4 x = ((const float4*)(ws_f + OFF_PART +
                                    ((size_t)p * B + b) * H))[c4];
        s.x += x.x; s.y += x.y; s.z += x.z; s.w += x.w;
    }

    __shared__ float4 red[4][64];
    red[psub][lane] = s;
    __syncthreads();
    if (psub == 0) {
        float4 a0 = red[0][lane], a1 = red[1][lane],
               a2 = red[2][lane], a3 = red[3][lane];
        float4 sm = make_float4(a0.x + a1.x + a2.x + a3.x,
                                a0.y + a1.y + a2.y + a3.y,
                                a0.z + a1.z + a2.z + a3.z,
                                a0.w + a1.w + a2.w + a3.w);

        float w0 = pw[0], w1 = pw[1], w2 = pw[2];
        float m  = fmaxf(w0, fmaxf(w1, w2));
        float e0 = expf(w0 - m), e1 = expf(w1 - m), e2 = expf(w2 - m);
        float invs = 1.f / (e0 + e1 + e2);

        float4 hil = ((const float4*)(ws_f + OFF_OUTS + (size_t)b * H))[c4];
        float4 can = ((const float4*)(ws_f + OFF_OUTS + ((size_t)B + b) * H))[c4];
        const float il = 1.0f / (float)L;  // dragon weights exactly 0 -> uniform
        float4 o;
        o.x = (e0 * hil.x + e1 * can.x + e2 * (sm.x * il)) * invs;
        o.y = (e0 * hil.y + e1 * can.y + e2 * (sm.y * il)) * invs;
        o.z = (e0 * hil.z + e1 * can.z + e2 * (sm.z * il)) * invs;
        o.w = (e0 * hil.w + e1 * can.w + e2 * (sm.w * il)) * invs;
        ((float4*)(out + (size_t)b * H))[c4] = o;
    }
}

extern "C" void kernel_launch(void* const* d_in, const int* in_sizes, int n_in,
                              void* d_out, int out_size, void* d_ws, size_t ws_size,
                              hipStream_t stream) {
    const float* q  = (const float*)d_in[0];
    const float* k  = (const float*)d_in[1];
    const float* v  = (const float*)d_in[2];
    const float* pw = (const float*)d_in[3];
    const int* qidx = (const int*)d_in[4];

    float* ws_f = (float*)d_ws;

    mega_kernel<<<16 + CPB * B, 512, 0, stream>>>(q, k, v, qidx, ws_f);
    combine_kernel<<<dim3(B, 4), 256, 0, stream>>>(pw, ws_f, (float*)d_out);
}